// Round 14
// baseline (324.553 us; speedup 1.0000x reference)
//
#include <hip/hip_runtime.h>

// ---------- types ----------
typedef __attribute__((ext_vector_type(8))) short bf16x8;
typedef __attribute__((ext_vector_type(4))) float f32x4;

#define T_SEQ   2048
#define DIM     3072
#define NQH     32
#define NKVH    8
#define HD      128
#define QDIM    4096
#define KVDIM   1024
#define QKVDIM  6144

#define AS1 __attribute__((address_space(1)))
#define AS3 __attribute__((address_space(3)))

static __device__ __forceinline__ unsigned short f2bf(float f) {
  unsigned u = __float_as_uint(f);
  u += 0x7FFFu + ((u >> 16) & 1u);          // RNE
  return (unsigned short)(u >> 16);
}
static __device__ __forceinline__ float bf2f(unsigned short h) {
  return __uint_as_float(((unsigned)h) << 16);
}
// packed f32x2 -> bf16x2 (RNE), 1 instruction
static __device__ __forceinline__ unsigned pkbf(float lo, float hi) {
  unsigned r;
  asm("v_cvt_pk_bf16_f32 %0, %1, %2" : "=v"(r) : "v"(lo), "v"(hi));
  return r;
}

// async global->LDS, 16B per lane; LDS dest must be linear in lane order (rule 21)
static __device__ __forceinline__ void gload_lds16(const unsigned short* g, unsigned short* l) {
  __builtin_amdgcn_global_load_lds((AS1 void*)(g), (AS3 void*)(l), 16, 0, 0);
}

// ---------- fused fp32 -> bf16 convert: x, wq, wk, wv (one launch) ----------
__global__ void cvt_all(const float* __restrict__ x,  const float* __restrict__ wq,
                        const float* __restrict__ wk, const float* __restrict__ wv,
                        unsigned short* __restrict__ xb,
                        unsigned short* __restrict__ wqkvb) {
  const int N0 = 1572864;                    // x:  2048*3072/4
  const int E1 = N0 + 3145728;               // wq: 4096*3072/4
  const int E2 = E1 + 786432;                // wk
  const int E3 = E2 + 786432;                // wv
  const int stride = gridDim.x * blockDim.x;
  for (int i = blockIdx.x * blockDim.x + threadIdx.x; i < E3; i += stride) {
    const float* s; unsigned short* d; int off;
    if (i < N0)      { s = x;  d = xb;               off = i; }
    else if (i < E1) { s = wq; d = wqkvb;            off = i - N0; }
    else if (i < E2) { s = wk; d = wqkvb + 12582912; off = i - E1; }
    else             { s = wv; d = wqkvb + 15728640; off = i - E2; }
    float4 v = reinterpret_cast<const float4*>(s)[off];
    ushort4 o;
    o.x = f2bf(v.x); o.y = f2bf(v.y); o.z = f2bf(v.z); o.w = f2bf(v.w);
    reinterpret_cast<ushort4*>(d + (size_t)off * 4)[0] = o;
  }
}

// ---------- GEMM: C[M,N] = A[M,K] * B[N,K]^T, bf16 in, f32 or bf16 out ----------
// 128x128 tile, 4 waves (2x2 of 64x64), BK=64, m97 structure. COLUMN-panel XCD
// mapping (R13 win): each XCD owns nbx/8 B-columns (L2-resident) x all M-panels.
// NCVT>0: the last NCVT blocks instead stream-convert wo fp32->bf16 (no pinned
// L2 set in this kernel -> near-free; this killed attn in R10 via KV eviction).
template<int OUTBF, int NCVT>
__global__ __launch_bounds__(256) void gemm_bt(
    const unsigned short* __restrict__ A, const unsigned short* __restrict__ B,
    float* __restrict__ Cf, unsigned short* __restrict__ Cb,
    int M, int N, int K,
    const float* __restrict__ cvsrc, unsigned short* __restrict__ cvdst) {
  if (NCVT > 0 && (int)blockIdx.x >= (int)gridDim.x - NCVT) {
    const int total = 3145728;               // 3072*4096/4
    int base = ((int)blockIdx.x - ((int)gridDim.x - NCVT)) * 256 + threadIdx.x;
    for (int i = base; i < total; i += NCVT * 256) {
      float4 v = reinterpret_cast<const float4*>(cvsrc)[i];
      ushort4 o;
      o.x = f2bf(v.x); o.y = f2bf(v.y); o.z = f2bf(v.z); o.w = f2bf(v.w);
      reinterpret_cast<ushort4*>(cvdst + (size_t)i * 4)[0] = o;
    }
    return;
  }
  __shared__ unsigned short la[128 * 64];
  __shared__ unsigned short lb[128 * 64];
  const int nbx = N >> 7;
  const int cpx = nbx >> 3;                 // B-column panels per XCD
  const int bid0 = blockIdx.x;
  const int xcd = bid0 & 7;
  const int ii = bid0 >> 3;
  const int bx = cpx * xcd + (ii % cpx);
  const int by = ii / cpx;
  const int tid = threadIdx.x;
  const int ln = tid & 63;
  const int wave = tid >> 6;
  const int lr = ln & 15, lg = ln >> 4;
  const int wr = wave >> 1, wc = wave & 1;
  const int rowA0 = by << 7, rowB0 = bx << 7;

  f32x4 acc[4][4] = {};

  const int ktn = K >> 6;
  for (int kt = 0; kt < ktn; kt++) {
    __syncthreads();                        // prev tile's reads done before overwrite
#pragma unroll
    for (int it = 0; it < 4; it++) {
      int ci = it * 256 + tid;              // linear LDS chunk id (r = ci>>3, pos = ci&7)
      int r = ci >> 3, cpos = ci & 7;
      int c = cpos ^ (r & 7);               // pre-swizzled source chunk
      gload_lds16(A + (size_t)(rowA0 + r) * K + kt * 64 + c * 8, &la[ci * 8]);
      gload_lds16(B + (size_t)(rowB0 + r) * K + kt * 64 + c * 8, &lb[ci * 8]);
    }
    __syncthreads();                        // drains vmcnt -> tiles visible
#pragma unroll
    for (int kk = 0; kk < 2; kk++) {
      bf16x8 af[4], bfr[4];
#pragma unroll
      for (int mi = 0; mi < 4; mi++) {
        int r = wr * 64 + mi * 16 + lr;
        int p = (kk * 4 + lg) ^ (r & 7);
        af[mi] = *reinterpret_cast<const bf16x8*>(&la[r * 64 + p * 8]);
      }
#pragma unroll
      for (int ni = 0; ni < 4; ni++) {
        int r = wc * 64 + ni * 16 + lr;
        int p = (kk * 4 + lg) ^ (r & 7);
        bfr[ni] = *reinterpret_cast<const bf16x8*>(&lb[r * 64 + p * 8]);
      }
#pragma unroll
      for (int mi = 0; mi < 4; mi++)
#pragma unroll
        for (int ni = 0; ni < 4; ni++)
          acc[mi][ni] = __builtin_amdgcn_mfma_f32_16x16x32_bf16(af[mi], bfr[ni], acc[mi][ni], 0, 0, 0);
    }
  }
#pragma unroll
  for (int mi = 0; mi < 4; mi++)
#pragma unroll
    for (int ni = 0; ni < 4; ni++)
#pragma unroll
      for (int j = 0; j < 4; j++) {
        int r = rowA0 + wr * 64 + mi * 16 + lg * 4 + j;   // C/D: row=(l>>4)*4+j, col=l&15
        int cc = rowB0 + wc * 64 + ni * 16 + lr;
        if (OUTBF) Cb[(size_t)r * N + cc] = f2bf(acc[mi][ni][j]);
        else       Cf[(size_t)r * N + cc] = acc[mi][ni][j];
      }
}

// ---------- RoPE + repack (x4 vectorized): qkv [T,6144] -> q [T,4096], k [T,1024] ----------
__global__ void rope_repack(const unsigned short* __restrict__ qkv,
                            const float* __restrict__ fc, const float* __restrict__ fs,
                            unsigned short* __restrict__ qo, unsigned short* __restrict__ ko) {
  int idx = blockIdx.x * blockDim.x + threadIdx.x;   // T * 40 * 16
  int dv = (idx & 15) * 4;                           // d base: 0,4,...,60
  int hh = (idx >> 4) % 40;                          // 0..31 q heads, 32..39 k heads
  int t = idx / 640;
  const unsigned short* src = qkv + (size_t)t * QKVDIM + hh * 128;
  ushort4 xl = *reinterpret_cast<const ushort4*>(src + dv);
  ushort4 xh = *reinterpret_cast<const ushort4*>(src + dv + 64);
  float4 c4 = *reinterpret_cast<const float4*>(&fc[t * 64 + dv]);
  float4 s4 = *reinterpret_cast<const float4*>(&fs[t * 64 + dv]);
  float a0 = bf2f(xl.x), a1 = bf2f(xl.y), a2 = bf2f(xl.z), a3 = bf2f(xl.w);
  float b0 = bf2f(xh.x), b1 = bf2f(xh.y), b2 = bf2f(xh.z), b3 = bf2f(xh.w);
  uint2 lo, hi;
  lo.x = pkbf(a0 * c4.x - b0 * s4.x, a1 * c4.y - b1 * s4.y);
  lo.y = pkbf(a2 * c4.z - b2 * s4.z, a3 * c4.w - b3 * s4.w);
  hi.x = pkbf(b0 * c4.x + a0 * s4.x, b1 * c4.y + a1 * s4.y);
  hi.y = pkbf(b2 * c4.z + a2 * s4.z, b3 * c4.w + a3 * s4.w);
  unsigned short* dst;
  int dstride;
  if (hh < 32) { dst = qo + (size_t)t * QDIM + hh * 128; dstride = 0; (void)dstride; }
  else         { dst = ko + (size_t)t * KVDIM + (hh - 32) * 128; }
  *reinterpret_cast<uint2*>(dst + dv)      = lo;
  *reinterpret_cast<uint2*>(dst + dv + 64) = hi;
}

// ---------- V transpose: qkv[:,5120+c] -> vt[c][t]  (c = kh*128+d) ----------
__global__ void vtrans(const unsigned short* __restrict__ qkv, unsigned short* __restrict__ vt) {
  __shared__ unsigned short tile[64][68];
  int tb = blockIdx.x * 64, cb = blockIdx.y * 64;
  int tid = threadIdx.x;
#pragma unroll
  for (int i = 0; i < 16; i++) {
    int e = i * 256 + tid;
    int tl = e >> 6, cl = e & 63;
    tile[tl][cl] = qkv[(size_t)(tb + tl) * QKVDIM + 5120 + cb + cl];
  }
  __syncthreads();
#pragma unroll
  for (int i = 0; i < 16; i++) {
    int e = i * 256 + tid;
    int cl = e >> 6, tl = e & 63;
    vt[(size_t)(cb + cl) * T_SEQ + tb + tl] = tile[tl][cl];
  }
}

// ---------- causal GQA flash attention (verified R9 version, 512 blocks) ----------
__global__ __launch_bounds__(256) void attn_fwd(
    const unsigned short* __restrict__ q, const unsigned short* __restrict__ k,
    const unsigned short* __restrict__ vt, unsigned short* __restrict__ y) {
  __shared__ unsigned short k_lds[2][32 * 128];
  __shared__ unsigned short v_lds[2][128 * 32];
  __shared__ unsigned short p_lds[4][16 * 40];
  __shared__ float a_lds[4][16];
  const int tid = threadIdx.x;
  const int ln = tid & 63;
  const int wave = tid >> 6;
  const int lr = ln & 15, lg = ln >> 4;

  const int kh = blockIdx.x & 7;
  const int i = blockIdx.x >> 3;
  const int qh = i & 3;
  const int pr = i >> 2;
  const int qta = pr, qtb = 31 - pr;
  const int h = kh * 4 + qh;

  const int qra0 = qta * 64 + wave * 16, qrowa = qra0 + lr;
  const int qrb0 = qtb * 64 + wave * 16, qrowb = qrb0 + lr;
  const float SL2E = 0.08838834764831845f * 1.44269504088896f;
  const float NEGINF = -__builtin_inff();

  bf16x8 qfa[4], qfb[4];
  {
    const unsigned short* qba = q + (size_t)qrowa * QDIM + h * HD + lg * 8;
    const unsigned short* qbb = q + (size_t)qrowb * QDIM + h * HD + lg * 8;
#pragma unroll
    for (int dc = 0; dc < 4; dc++) {
      qfa[dc] = *reinterpret_cast<const bf16x8*>(qba + dc * 32);
      qfb[dc] = *reinterpret_cast<const bf16x8*>(qbb + dc * 32);
    }
  }

  f32x4 acca[8] = {}, accb[8] = {};
  float ma = NEGINF, la = 0.f, mb = NEGINF, lb = 0.f;

  const int krow0 = tid >> 4,  kcol0 = tid & 15;
  const int krow1 = 16 + krow0;
  const int vrow0 = tid >> 2,  vcol0 = tid & 3;
  const int vrow1 = 64 + vrow0;

  auto tile_compute = [&](int sb, int cur, const bf16x8 (&qf)[4], f32x4 (&acc)[8],
                          float& m, float& lsum, int qr0, int qrow) {
    f32x4 s0t = {0.f, 0.f, 0.f, 0.f}, s1t = {0.f, 0.f, 0.f, 0.f};
    __builtin_amdgcn_s_setprio(1);
#pragma unroll
    for (int dc = 0; dc < 4; dc++) {
      int c = lg + dc * 4;
      int p = c ^ (lr & 7);
      bf16x8 a0 = *reinterpret_cast<const bf16x8*>(&k_lds[cur][lr * 128 + p * 8]);
      bf16x8 a1 = *reinterpret_cast<const bf16x8*>(&k_lds[cur][(lr + 16) * 128 + p * 8]);
      s0t = __builtin_amdgcn_mfma_f32_16x16x32_bf16(a0, qf[dc], s0t, 0, 0, 0);
      s1t = __builtin_amdgcn_mfma_f32_16x16x32_bf16(a1, qf[dc], s1t, 0, 0, 0);
    }
    __builtin_amdgcn_s_setprio(0);

    float vv[8];
    if (sb + 31 <= qr0) {
#pragma unroll
      for (int jj = 0; jj < 4; jj++) { vv[jj] = s0t[jj]; vv[jj + 4] = s1t[jj]; }
    } else {
      const int base0 = sb + lg * 4;
#pragma unroll
      for (int jj = 0; jj < 4; jj++) {
        vv[jj]     = (base0 + jj      <= qrow) ? s0t[jj] : NEGINF;
        vv[jj + 4] = (base0 + jj + 16 <= qrow) ? s1t[jj] : NEGINF;
      }
    }

    float mx = fmaxf(fmaxf(fmaxf(vv[0], vv[1]), fmaxf(vv[2], vv[3])),
                     fmaxf(fmaxf(vv[4], vv[5]), fmaxf(vv[6], vv[7])));
    mx = fmaxf(mx, __shfl_xor(mx, 16));
    mx = fmaxf(mx, __shfl_xor(mx, 32));

    const bool doresc = __any(mx > m + 60.0f);
    const float mn = doresc ? fmaxf(m, mx) : m;

    float p[8], ps = 0.f;
#pragma unroll
    for (int ii = 0; ii < 8; ii++) { p[ii] = exp2f((vv[ii] - mn) * SL2E); ps += p[ii]; }
    ps += __shfl_xor(ps, 16);
    ps += __shfl_xor(ps, 32);

    uint2 w0, w1;
    w0.x = pkbf(p[0], p[1]); w0.y = pkbf(p[2], p[3]);
    w1.x = pkbf(p[4], p[5]); w1.y = pkbf(p[6], p[7]);
    *reinterpret_cast<uint2*>(&p_lds[wave][lr * 40 + lg * 4])      = w0;
    *reinterpret_cast<uint2*>(&p_lds[wave][lr * 40 + 16 + lg * 4]) = w1;

    if (doresc) {
      const float alpha = exp2f((m - mn) * SL2E);
      lsum = lsum * alpha + ps;
      m = mn;
      a_lds[wave][lr] = alpha;
      asm volatile("s_waitcnt lgkmcnt(0)" ::: "memory");
      float4 a4 = *reinterpret_cast<const float4*>(&a_lds[wave][lg * 4]);
#pragma unroll
      for (int dc2 = 0; dc2 < 8; dc2++) {
        acc[dc2][0] *= a4.x; acc[dc2][1] *= a4.y;
        acc[dc2][2] *= a4.z; acc[dc2][3] *= a4.w;
      }
    } else {
      lsum += ps;
      asm volatile("s_waitcnt lgkmcnt(0)" ::: "memory");
    }

    bf16x8 pa = *reinterpret_cast<const bf16x8*>(&p_lds[wave][lr * 40 + lg * 8]);
    __builtin_amdgcn_s_setprio(1);
#pragma unroll
    for (int dc2 = 0; dc2 < 8; dc2++) {
      int d = dc2 * 16 + lr;
      int p2 = lg ^ ((d >> 1) & 3);
      bf16x8 bv = *reinterpret_cast<const bf16x8*>(&v_lds[cur][d * 32 + p2 * 8]);
      acc[dc2] = __builtin_amdgcn_mfma_f32_16x16x32_bf16(pa, bv, acc[dc2], 0, 0, 0);
    }
    __builtin_amdgcn_s_setprio(0);
  };

  const int ntiles = (qtb * 64 + 95) >> 5;

  {
    bf16x8 kr0 = *reinterpret_cast<const bf16x8*>(k + (size_t)krow0 * KVDIM + kh * HD + kcol0 * 8);
    bf16x8 kr1 = *reinterpret_cast<const bf16x8*>(k + (size_t)krow1 * KVDIM + kh * HD + kcol0 * 8);
    bf16x8 vr0 = *reinterpret_cast<const bf16x8*>(vt + (size_t)(kh * HD + vrow0) * T_SEQ + vcol0 * 8);
    bf16x8 vr1 = *reinterpret_cast<const bf16x8*>(vt + (size_t)(kh * HD + vrow1) * T_SEQ + vcol0 * 8);
    *reinterpret_cast<bf16x8*>(&k_lds[0][krow0 * 128 + (kcol0 ^ (krow0 & 7)) * 8]) = kr0;
    *reinterpret_cast<bf16x8*>(&k_lds[0][krow1 * 128 + (kcol0 ^ (krow1 & 7)) * 8]) = kr1;
    *reinterpret_cast<bf16x8*>(&v_lds[0][vrow0 * 32 + (vcol0 ^ ((vrow0 >> 1) & 3)) * 8]) = vr0;
    *reinterpret_cast<bf16x8*>(&v_lds[0][vrow1 * 32 + (vcol0 ^ ((vrow1 >> 1) & 3)) * 8]) = vr1;
  }
  __syncthreads();

  for (int st = 0; st < ntiles; st++) {
    const int sb = st * 32;
    const int cur = st & 1;
    const bool more = (st + 1 < ntiles);

    bf16x8 kr0, kr1, vr0, vr1;
    if (more) {
      const int sb1 = sb + 32;
      kr0 = *reinterpret_cast<const bf16x8*>(k + (size_t)(sb1 + krow0) * KVDIM + kh * HD + kcol0 * 8);
      kr1 = *reinterpret_cast<const bf16x8*>(k + (size_t)(sb1 + krow1) * KVDIM + kh * HD + kcol0 * 8);
      vr0 = *reinterpret_cast<const bf16x8*>(vt + (size_t)(kh * HD + vrow0) * T_SEQ + sb1 + vcol0 * 8);
      vr1 = *reinterpret_cast<const bf16x8*>(vt + (size_t)(kh * HD + vrow1) * T_SEQ + sb1 + vcol0 * 8);
    }

    if (sb <= qrb0 + 15) tile_compute(sb, cur, qfb, accb, mb, lb, qrb0, qrowb);
    if (sb <= qra0 + 15) tile_compute(sb, cur, qfa, acca, ma, la, qra0, qrowa);

    if (more) {
      const int nxt = cur ^ 1;
      *reinterpret_cast<bf16x8*>(&k_lds[nxt][krow0 * 128 + (kcol0 ^ (krow0 & 7)) * 8]) = kr0;
      *reinterpret_cast<bf16x8*>(&k_lds[nxt][krow1 * 128 + (kcol0 ^ (krow1 & 7)) * 8]) = kr1;
      *reinterpret_cast<bf16x8*>(&v_lds[nxt][vrow0 * 32 + (vcol0 ^ ((vrow0 >> 1) & 3)) * 8]) = vr0;
      *reinterpret_cast<bf16x8*>(&v_lds[nxt][vrow1 * 32 + (vcol0 ^ ((vrow1 >> 1) & 3)) * 8]) = vr1;
      __syncthreads();
    }
  }

  a_lds[wave][lr] = 1.0f / lb;
  asm volatile("s_waitcnt lgkmcnt(0)" ::: "memory");
  float4 l4 = *reinterpret_cast<const float4*>(&a_lds[wave][lg * 4]);
  {
    float li[4] = {l4.x, l4.y, l4.z, l4.w};
#pragma unroll
    for (int jj = 0; jj < 4; jj++) {
      int r = qrb0 + lg * 4 + jj;
#pragma unroll
      for (int dc2 = 0; dc2 < 8; dc2++)
        y[(size_t)r * QDIM + h * HD + dc2 * 16 + lr] = f2bf(accb[dc2][jj] * li[jj]);
    }
  }
  a_lds[wave][lr] = 1.0f / la;
  asm volatile("s_waitcnt lgkmcnt(0)" ::: "memory");
  l4 = *reinterpret_cast<const float4*>(&a_lds[wave][lg * 4]);
  {
    float li[4] = {l4.x, l4.y, l4.z, l4.w};
#pragma unroll
    for (int jj = 0; jj < 4; jj++) {
      int r = qra0 + lg * 4 + jj;
#pragma unroll
      for (int dc2 = 0; dc2 < 8; dc2++)
        y[(size_t)r * QDIM + h * HD + dc2 * 16 + lr] = f2bf(acca[dc2][jj] * li[jj]);
    }
  }
}

// ---------- launch ----------
extern "C" void kernel_launch(void* const* d_in, const int* in_sizes, int n_in,
                              void* d_out, int out_size, void* d_ws, size_t ws_size,
                              hipStream_t stream) {
  (void)in_sizes; (void)n_in; (void)out_size; (void)ws_size;
  const float* x    = (const float*)d_in[0];
  const float* fcos = (const float*)d_in[1];
  const float* fsin = (const float*)d_in[2];
  const float* wq   = (const float*)d_in[4];
  const float* wk   = (const float*)d_in[5];
  const float* wv   = (const float*)d_in[6];
  const float* wo   = (const float*)d_in[7];
  float* out = (float*)d_out;
  char* ws = (char*)d_ws;

  // workspace layout (peak 100.7 MB)
  unsigned short* x_bf    = (unsigned short*)(ws);                    // 12.6 MB [phase 1]
  unsigned short* wqkv_bf = (unsigned short*)(ws + 12582912);         // 37.7 MB [phase 1]
  unsigned short* qkv_bf  = (unsigned short*)(ws + 50331648);         // 25.2 MB [phase 1-2]
  unsigned short* q_bf    = (unsigned short*)(ws);                    // 16.8 MB [phase 2+]
  unsigned short* k_bf    = (unsigned short*)(ws + 16777216);         //  4.2 MB
  unsigned short* vt_bf   = (unsigned short*)(ws + 20971520);         //  4.2 MB
  unsigned short* y_bf    = (unsigned short*)(ws + 25165824);         // 16.8 MB
  unsigned short* wo_bf   = (unsigned short*)(ws + 75497472);         // 25.2 MB (own region)

  // phase 1: convert x+wqkv; QKV GEMM (blocks 0-767) + wo convert (768-895)
  cvt_all<<<4096, 256, 0, stream>>>(x, wq, wk, wv, x_bf, wqkv_bf);
  gemm_bt<1, 128><<<896, 256, 0, stream>>>(x_bf, wqkv_bf, nullptr, qkv_bf,
                                           2048, 6144, 3072, wo, wo_bf);

  // phase 2: RoPE + repack (x4 vectorized), V transpose
  rope_repack<<<5120, 256, 0, stream>>>(qkv_bf, fcos, fsin, q_bf, k_bf);
  vtrans<<<dim3(32, 16), 256, 0, stream>>>(qkv_bf, vt_bf);

  // phase 3/4: attention, output GEMM
  attn_fwd<<<512, 256, 0, stream>>>(q_bf, k_bf, vt_bf, y_bf);
  gemm_bt<0, 0><<<384, 256, 0, stream>>>(y_bf, wo_bf, out, nullptr,
                                         2048, 3072, 4096, nullptr, nullptr);
}

// Round 15
// 322.880 us; speedup vs baseline: 1.0052x; 1.0052x over previous
//
#include <hip/hip_runtime.h>

// ---------- types ----------
typedef __attribute__((ext_vector_type(8))) short bf16x8;
typedef __attribute__((ext_vector_type(4))) float f32x4;

#define T_SEQ   2048
#define DIM     3072
#define NQH     32
#define NKVH    8
#define HD      128
#define QDIM    4096
#define KVDIM   1024
#define QKVDIM  6144

#define AS1 __attribute__((address_space(1)))
#define AS3 __attribute__((address_space(3)))

static __device__ __forceinline__ unsigned short f2bf(float f) {
  unsigned u = __float_as_uint(f);
  u += 0x7FFFu + ((u >> 16) & 1u);          // RNE
  return (unsigned short)(u >> 16);
}
static __device__ __forceinline__ float bf2f(unsigned short h) {
  return __uint_as_float(((unsigned)h) << 16);
}
// packed f32x2 -> bf16x2 (RNE), 1 instruction
static __device__ __forceinline__ unsigned pkbf(float lo, float hi) {
  unsigned r;
  asm("v_cvt_pk_bf16_f32 %0, %1, %2" : "=v"(r) : "v"(lo), "v"(hi));
  return r;
}

// async global->LDS, 16B per lane; LDS dest must be linear in lane order (rule 21)
static __device__ __forceinline__ void gload_lds16(const unsigned short* g, unsigned short* l) {
  __builtin_amdgcn_global_load_lds((AS1 void*)(g), (AS3 void*)(l), 16, 0, 0);
}

// ---------- fused fp32 -> bf16 convert: x, wq, wk, wv (one launch) ----------
__global__ void cvt_all(const float* __restrict__ x,  const float* __restrict__ wq,
                        const float* __restrict__ wk, const float* __restrict__ wv,
                        unsigned short* __restrict__ xb,
                        unsigned short* __restrict__ wqkvb) {
  const int N0 = 1572864;                    // x:  2048*3072/4
  const int E1 = N0 + 3145728;               // wq: 4096*3072/4
  const int E2 = E1 + 786432;                // wk
  const int E3 = E2 + 786432;                // wv
  const int stride = gridDim.x * blockDim.x;
  for (int i = blockIdx.x * blockDim.x + threadIdx.x; i < E3; i += stride) {
    const float* s; unsigned short* d; int off;
    if (i < N0)      { s = x;  d = xb;               off = i; }
    else if (i < E1) { s = wq; d = wqkvb;            off = i - N0; }
    else if (i < E2) { s = wk; d = wqkvb + 12582912; off = i - E1; }
    else             { s = wv; d = wqkvb + 15728640; off = i - E2; }
    float4 v = reinterpret_cast<const float4*>(s)[off];
    ushort4 o;
    o.x = f2bf(v.x); o.y = f2bf(v.y); o.z = f2bf(v.z); o.w = f2bf(v.w);
    reinterpret_cast<ushort4*>(d + (size_t)off * 4)[0] = o;
  }
}

// ---------- GEMM: C[M,N] = A[M,K] * B[N,K]^T, bf16 in, f32 or bf16 out ----------
// 128x128 tile, 4 waves (2x2 of 64x64), BK=64, m97 structure. COLUMN-panel XCD
// mapping (R13 win): each XCD owns nbx/8 B-columns (L2-resident) x all M-panels.
// NCVT>0: the FIRST NCVT blocks stream-convert wo fp32->bf16 — dispatched first,
// they overlap the GEMM instead of forming a serial tail (R14 lesson).
template<int OUTBF, int NCVT>
__global__ __launch_bounds__(256) void gemm_bt(
    const unsigned short* __restrict__ A, const unsigned short* __restrict__ B,
    float* __restrict__ Cf, unsigned short* __restrict__ Cb,
    int M, int N, int K,
    const float* __restrict__ cvsrc, unsigned short* __restrict__ cvdst) {
  if (NCVT > 0 && (int)blockIdx.x < NCVT) {
    const int total = 3145728;               // 3072*4096/4
    for (int i = (int)blockIdx.x * 256 + threadIdx.x; i < total; i += NCVT * 256) {
      float4 v = reinterpret_cast<const float4*>(cvsrc)[i];
      ushort4 o;
      o.x = f2bf(v.x); o.y = f2bf(v.y); o.z = f2bf(v.z); o.w = f2bf(v.w);
      reinterpret_cast<ushort4*>(cvdst + (size_t)i * 4)[0] = o;
    }
    return;
  }
  __shared__ unsigned short la[128 * 64];
  __shared__ unsigned short lb[128 * 64];
  const int nbx = N >> 7;
  const int cpx = nbx >> 3;                 // B-column panels per XCD
  const int bid0 = (int)blockIdx.x - NCVT;
  const int xcd = bid0 & 7;
  const int ii = bid0 >> 3;
  const int bx = cpx * xcd + (ii % cpx);
  const int by = ii / cpx;
  const int tid = threadIdx.x;
  const int ln = tid & 63;
  const int wave = tid >> 6;
  const int lr = ln & 15, lg = ln >> 4;
  const int wr = wave >> 1, wc = wave & 1;
  const int rowA0 = by << 7, rowB0 = bx << 7;

  f32x4 acc[4][4] = {};

  const int ktn = K >> 6;
  for (int kt = 0; kt < ktn; kt++) {
    __syncthreads();                        // prev tile's reads done before overwrite
#pragma unroll
    for (int it = 0; it < 4; it++) {
      int ci = it * 256 + tid;              // linear LDS chunk id (r = ci>>3, pos = ci&7)
      int r = ci >> 3, cpos = ci & 7;
      int c = cpos ^ (r & 7);               // pre-swizzled source chunk
      gload_lds16(A + (size_t)(rowA0 + r) * K + kt * 64 + c * 8, &la[ci * 8]);
      gload_lds16(B + (size_t)(rowB0 + r) * K + kt * 64 + c * 8, &lb[ci * 8]);
    }
    __syncthreads();                        // drains vmcnt -> tiles visible
#pragma unroll
    for (int kk = 0; kk < 2; kk++) {
      bf16x8 af[4], bfr[4];
#pragma unroll
      for (int mi = 0; mi < 4; mi++) {
        int r = wr * 64 + mi * 16 + lr;
        int p = (kk * 4 + lg) ^ (r & 7);
        af[mi] = *reinterpret_cast<const bf16x8*>(&la[r * 64 + p * 8]);
      }
#pragma unroll
      for (int ni = 0; ni < 4; ni++) {
        int r = wc * 64 + ni * 16 + lr;
        int p = (kk * 4 + lg) ^ (r & 7);
        bfr[ni] = *reinterpret_cast<const bf16x8*>(&lb[r * 64 + p * 8]);
      }
#pragma unroll
      for (int mi = 0; mi < 4; mi++)
#pragma unroll
        for (int ni = 0; ni < 4; ni++)
          acc[mi][ni] = __builtin_amdgcn_mfma_f32_16x16x32_bf16(af[mi], bfr[ni], acc[mi][ni], 0, 0, 0);
    }
  }
#pragma unroll
  for (int mi = 0; mi < 4; mi++)
#pragma unroll
    for (int ni = 0; ni < 4; ni++)
#pragma unroll
      for (int j = 0; j < 4; j++) {
        int r = rowA0 + wr * 64 + mi * 16 + lg * 4 + j;   // C/D: row=(l>>4)*4+j, col=l&15
        int cc = rowB0 + wc * 64 + ni * 16 + lr;
        if (OUTBF) Cb[(size_t)r * N + cc] = f2bf(acc[mi][ni][j]);
        else       Cf[(size_t)r * N + cc] = acc[mi][ni][j];
      }
}

// ---------- RoPE + repack (x4 vectorized): qkv [T,6144] -> q [T,4096], k [T,1024] ----------
__global__ void rope_repack(const unsigned short* __restrict__ qkv,
                            const float* __restrict__ fc, const float* __restrict__ fs,
                            unsigned short* __restrict__ qo, unsigned short* __restrict__ ko) {
  int idx = blockIdx.x * blockDim.x + threadIdx.x;   // T * 40 * 16
  int dv = (idx & 15) * 4;                           // d base: 0,4,...,60
  int hh = (idx >> 4) % 40;                          // 0..31 q heads, 32..39 k heads
  int t = idx / 640;
  const unsigned short* src = qkv + (size_t)t * QKVDIM + hh * 128;
  ushort4 xl = *reinterpret_cast<const ushort4*>(src + dv);
  ushort4 xh = *reinterpret_cast<const ushort4*>(src + dv + 64);
  float4 c4 = *reinterpret_cast<const float4*>(&fc[t * 64 + dv]);
  float4 s4 = *reinterpret_cast<const float4*>(&fs[t * 64 + dv]);
  float a0 = bf2f(xl.x), a1 = bf2f(xl.y), a2 = bf2f(xl.z), a3 = bf2f(xl.w);
  float b0 = bf2f(xh.x), b1 = bf2f(xh.y), b2 = bf2f(xh.z), b3 = bf2f(xh.w);
  uint2 lo, hi;
  lo.x = pkbf(a0 * c4.x - b0 * s4.x, a1 * c4.y - b1 * s4.y);
  lo.y = pkbf(a2 * c4.z - b2 * s4.z, a3 * c4.w - b3 * s4.w);
  hi.x = pkbf(b0 * c4.x + a0 * s4.x, b1 * c4.y + a1 * s4.y);
  hi.y = pkbf(b2 * c4.z + a2 * s4.z, b3 * c4.w + a3 * s4.w);
  unsigned short* dst;
  if (hh < 32) { dst = qo + (size_t)t * QDIM + hh * 128; }
  else         { dst = ko + (size_t)t * KVDIM + (hh - 32) * 128; }
  *reinterpret_cast<uint2*>(dst + dv)      = lo;
  *reinterpret_cast<uint2*>(dst + dv + 64) = hi;
}

// ---------- V transpose: qkv[:,5120+c] -> vt[c][t]  (c = kh*128+d) ----------
__global__ void vtrans(const unsigned short* __restrict__ qkv, unsigned short* __restrict__ vt) {
  __shared__ unsigned short tile[64][68];
  int tb = blockIdx.x * 64, cb = blockIdx.y * 64;
  int tid = threadIdx.x;
#pragma unroll
  for (int i = 0; i < 16; i++) {
    int e = i * 256 + tid;
    int tl = e >> 6, cl = e & 63;
    tile[tl][cl] = qkv[(size_t)(tb + tl) * QKVDIM + 5120 + cb + cl];
  }
  __syncthreads();
#pragma unroll
  for (int i = 0; i < 16; i++) {
    int e = i * 256 + tid;
    int cl = e >> 6, tl = e & 63;
    vt[(size_t)(cb + cl) * T_SEQ + tb + tl] = tile[tl][cl];
  }
}

// ---------- causal GQA flash attention (verified R9 version, 512 blocks) ----------
__global__ __launch_bounds__(256) void attn_fwd(
    const unsigned short* __restrict__ q, const unsigned short* __restrict__ k,
    const unsigned short* __restrict__ vt, unsigned short* __restrict__ y) {
  __shared__ unsigned short k_lds[2][32 * 128];
  __shared__ unsigned short v_lds[2][128 * 32];
  __shared__ unsigned short p_lds[4][16 * 40];
  __shared__ float a_lds[4][16];
  const int tid = threadIdx.x;
  const int ln = tid & 63;
  const int wave = tid >> 6;
  const int lr = ln & 15, lg = ln >> 4;

  const int kh = blockIdx.x & 7;
  const int i = blockIdx.x >> 3;
  const int qh = i & 3;
  const int pr = i >> 2;
  const int qta = pr, qtb = 31 - pr;
  const int h = kh * 4 + qh;

  const int qra0 = qta * 64 + wave * 16, qrowa = qra0 + lr;
  const int qrb0 = qtb * 64 + wave * 16, qrowb = qrb0 + lr;
  const float SL2E = 0.08838834764831845f * 1.44269504088896f;
  const float NEGINF = -__builtin_inff();

  bf16x8 qfa[4], qfb[4];
  {
    const unsigned short* qba = q + (size_t)qrowa * QDIM + h * HD + lg * 8;
    const unsigned short* qbb = q + (size_t)qrowb * QDIM + h * HD + lg * 8;
#pragma unroll
    for (int dc = 0; dc < 4; dc++) {
      qfa[dc] = *reinterpret_cast<const bf16x8*>(qba + dc * 32);
      qfb[dc] = *reinterpret_cast<const bf16x8*>(qbb + dc * 32);
    }
  }

  f32x4 acca[8] = {}, accb[8] = {};
  float ma = NEGINF, la = 0.f, mb = NEGINF, lb = 0.f;

  const int krow0 = tid >> 4,  kcol0 = tid & 15;
  const int krow1 = 16 + krow0;
  const int vrow0 = tid >> 2,  vcol0 = tid & 3;
  const int vrow1 = 64 + vrow0;

  auto tile_compute = [&](int sb, int cur, const bf16x8 (&qf)[4], f32x4 (&acc)[8],
                          float& m, float& lsum, int qr0, int qrow) {
    f32x4 s0t = {0.f, 0.f, 0.f, 0.f}, s1t = {0.f, 0.f, 0.f, 0.f};
    __builtin_amdgcn_s_setprio(1);
#pragma unroll
    for (int dc = 0; dc < 4; dc++) {
      int c = lg + dc * 4;
      int p = c ^ (lr & 7);
      bf16x8 a0 = *reinterpret_cast<const bf16x8*>(&k_lds[cur][lr * 128 + p * 8]);
      bf16x8 a1 = *reinterpret_cast<const bf16x8*>(&k_lds[cur][(lr + 16) * 128 + p * 8]);
      s0t = __builtin_amdgcn_mfma_f32_16x16x32_bf16(a0, qf[dc], s0t, 0, 0, 0);
      s1t = __builtin_amdgcn_mfma_f32_16x16x32_bf16(a1, qf[dc], s1t, 0, 0, 0);
    }
    __builtin_amdgcn_s_setprio(0);

    float vv[8];
    if (sb + 31 <= qr0) {
#pragma unroll
      for (int jj = 0; jj < 4; jj++) { vv[jj] = s0t[jj]; vv[jj + 4] = s1t[jj]; }
    } else {
      const int base0 = sb + lg * 4;
#pragma unroll
      for (int jj = 0; jj < 4; jj++) {
        vv[jj]     = (base0 + jj      <= qrow) ? s0t[jj] : NEGINF;
        vv[jj + 4] = (base0 + jj + 16 <= qrow) ? s1t[jj] : NEGINF;
      }
    }

    float mx = fmaxf(fmaxf(fmaxf(vv[0], vv[1]), fmaxf(vv[2], vv[3])),
                     fmaxf(fmaxf(vv[4], vv[5]), fmaxf(vv[6], vv[7])));
    mx = fmaxf(mx, __shfl_xor(mx, 16));
    mx = fmaxf(mx, __shfl_xor(mx, 32));

    const bool doresc = __any(mx > m + 60.0f);
    const float mn = doresc ? fmaxf(m, mx) : m;

    float p[8], ps = 0.f;
#pragma unroll
    for (int ii = 0; ii < 8; ii++) { p[ii] = exp2f((vv[ii] - mn) * SL2E); ps += p[ii]; }
    ps += __shfl_xor(ps, 16);
    ps += __shfl_xor(ps, 32);

    uint2 w0, w1;
    w0.x = pkbf(p[0], p[1]); w0.y = pkbf(p[2], p[3]);
    w1.x = pkbf(p[4], p[5]); w1.y = pkbf(p[6], p[7]);
    *reinterpret_cast<uint2*>(&p_lds[wave][lr * 40 + lg * 4])      = w0;
    *reinterpret_cast<uint2*>(&p_lds[wave][lr * 40 + 16 + lg * 4]) = w1;

    if (doresc) {
      const float alpha = exp2f((m - mn) * SL2E);
      lsum = lsum * alpha + ps;
      m = mn;
      a_lds[wave][lr] = alpha;
      asm volatile("s_waitcnt lgkmcnt(0)" ::: "memory");
      float4 a4 = *reinterpret_cast<const float4*>(&a_lds[wave][lg * 4]);
#pragma unroll
      for (int dc2 = 0; dc2 < 8; dc2++) {
        acc[dc2][0] *= a4.x; acc[dc2][1] *= a4.y;
        acc[dc2][2] *= a4.z; acc[dc2][3] *= a4.w;
      }
    } else {
      lsum += ps;
      asm volatile("s_waitcnt lgkmcnt(0)" ::: "memory");
    }

    bf16x8 pa = *reinterpret_cast<const bf16x8*>(&p_lds[wave][lr * 40 + lg * 8]);
    __builtin_amdgcn_s_setprio(1);
#pragma unroll
    for (int dc2 = 0; dc2 < 8; dc2++) {
      int d = dc2 * 16 + lr;
      int p2 = lg ^ ((d >> 1) & 3);
      bf16x8 bv = *reinterpret_cast<const bf16x8*>(&v_lds[cur][d * 32 + p2 * 8]);
      acc[dc2] = __builtin_amdgcn_mfma_f32_16x16x32_bf16(pa, bv, acc[dc2], 0, 0, 0);
    }
    __builtin_amdgcn_s_setprio(0);
  };

  const int ntiles = (qtb * 64 + 95) >> 5;

  {
    bf16x8 kr0 = *reinterpret_cast<const bf16x8*>(k + (size_t)krow0 * KVDIM + kh * HD + kcol0 * 8);
    bf16x8 kr1 = *reinterpret_cast<const bf16x8*>(k + (size_t)krow1 * KVDIM + kh * HD + kcol0 * 8);
    bf16x8 vr0 = *reinterpret_cast<const bf16x8*>(vt + (size_t)(kh * HD + vrow0) * T_SEQ + vcol0 * 8);
    bf16x8 vr1 = *reinterpret_cast<const bf16x8*>(vt + (size_t)(kh * HD + vrow1) * T_SEQ + vcol0 * 8);
    *reinterpret_cast<bf16x8*>(&k_lds[0][krow0 * 128 + (kcol0 ^ (krow0 & 7)) * 8]) = kr0;
    *reinterpret_cast<bf16x8*>(&k_lds[0][krow1 * 128 + (kcol0 ^ (krow1 & 7)) * 8]) = kr1;
    *reinterpret_cast<bf16x8*>(&v_lds[0][vrow0 * 32 + (vcol0 ^ ((vrow0 >> 1) & 3)) * 8]) = vr0;
    *reinterpret_cast<bf16x8*>(&v_lds[0][vrow1 * 32 + (vcol0 ^ ((vrow1 >> 1) & 3)) * 8]) = vr1;
  }
  __syncthreads();

  for (int st = 0; st < ntiles; st++) {
    const int sb = st * 32;
    const int cur = st & 1;
    const bool more = (st + 1 < ntiles);

    bf16x8 kr0, kr1, vr0, vr1;
    if (more) {
      const int sb1 = sb + 32;
      kr0 = *reinterpret_cast<const bf16x8*>(k + (size_t)(sb1 + krow0) * KVDIM + kh * HD + kcol0 * 8);
      kr1 = *reinterpret_cast<const bf16x8*>(k + (size_t)(sb1 + krow1) * KVDIM + kh * HD + kcol0 * 8);
      vr0 = *reinterpret_cast<const bf16x8*>(vt + (size_t)(kh * HD + vrow0) * T_SEQ + sb1 + vcol0 * 8);
      vr1 = *reinterpret_cast<const bf16x8*>(vt + (size_t)(kh * HD + vrow1) * T_SEQ + sb1 + vcol0 * 8);
    }

    if (sb <= qrb0 + 15) tile_compute(sb, cur, qfb, accb, mb, lb, qrb0, qrowb);
    if (sb <= qra0 + 15) tile_compute(sb, cur, qfa, acca, ma, la, qra0, qrowa);

    if (more) {
      const int nxt = cur ^ 1;
      *reinterpret_cast<bf16x8*>(&k_lds[nxt][krow0 * 128 + (kcol0 ^ (krow0 & 7)) * 8]) = kr0;
      *reinterpret_cast<bf16x8*>(&k_lds[nxt][krow1 * 128 + (kcol0 ^ (krow1 & 7)) * 8]) = kr1;
      *reinterpret_cast<bf16x8*>(&v_lds[nxt][vrow0 * 32 + (vcol0 ^ ((vrow0 >> 1) & 3)) * 8]) = vr0;
      *reinterpret_cast<bf16x8*>(&v_lds[nxt][vrow1 * 32 + (vcol0 ^ ((vrow1 >> 1) & 3)) * 8]) = vr1;
      __syncthreads();
    }
  }

  a_lds[wave][lr] = 1.0f / lb;
  asm volatile("s_waitcnt lgkmcnt(0)" ::: "memory");
  float4 l4 = *reinterpret_cast<const float4*>(&a_lds[wave][lg * 4]);
  {
    float li[4] = {l4.x, l4.y, l4.z, l4.w};
#pragma unroll
    for (int jj = 0; jj < 4; jj++) {
      int r = qrb0 + lg * 4 + jj;
#pragma unroll
      for (int dc2 = 0; dc2 < 8; dc2++)
        y[(size_t)r * QDIM + h * HD + dc2 * 16 + lr] = f2bf(accb[dc2][jj] * li[jj]);
    }
  }
  a_lds[wave][lr] = 1.0f / la;
  asm volatile("s_waitcnt lgkmcnt(0)" ::: "memory");
  l4 = *reinterpret_cast<const float4*>(&a_lds[wave][lg * 4]);
  {
    float li[4] = {l4.x, l4.y, l4.z, l4.w};
#pragma unroll
    for (int jj = 0; jj < 4; jj++) {
      int r = qra0 + lg * 4 + jj;
#pragma unroll
      for (int dc2 = 0; dc2 < 8; dc2++)
        y[(size_t)r * QDIM + h * HD + dc2 * 16 + lr] = f2bf(acca[dc2][jj] * li[jj]);
    }
  }
}

// ---------- launch ----------
extern "C" void kernel_launch(void* const* d_in, const int* in_sizes, int n_in,
                              void* d_out, int out_size, void* d_ws, size_t ws_size,
                              hipStream_t stream) {
  (void)in_sizes; (void)n_in; (void)out_size; (void)ws_size;
  const float* x    = (const float*)d_in[0];
  const float* fcos = (const float*)d_in[1];
  const float* fsin = (const float*)d_in[2];
  const float* wq   = (const float*)d_in[4];
  const float* wk   = (const float*)d_in[5];
  const float* wv   = (const float*)d_in[6];
  const float* wo   = (const float*)d_in[7];
  float* out = (float*)d_out;
  char* ws = (char*)d_ws;

  // workspace layout (peak 100.7 MB)
  unsigned short* x_bf    = (unsigned short*)(ws);                    // 12.6 MB [phase 1]
  unsigned short* wqkv_bf = (unsigned short*)(ws + 12582912);         // 37.7 MB [phase 1]
  unsigned short* qkv_bf  = (unsigned short*)(ws + 50331648);         // 25.2 MB [phase 1-2]
  unsigned short* q_bf    = (unsigned short*)(ws);                    // 16.8 MB [phase 2+]
  unsigned short* k_bf    = (unsigned short*)(ws + 16777216);         //  4.2 MB
  unsigned short* vt_bf   = (unsigned short*)(ws + 20971520);         //  4.2 MB
  unsigned short* y_bf    = (unsigned short*)(ws + 25165824);         // 16.8 MB
  unsigned short* wo_bf   = (unsigned short*)(ws + 75497472);         // 25.2 MB (own region)

  // phase 1: convert x+wqkv; wo convert (blocks 0-127) + QKV GEMM (128-895)
  cvt_all<<<4096, 256, 0, stream>>>(x, wq, wk, wv, x_bf, wqkv_bf);
  gemm_bt<1, 128><<<896, 256, 0, stream>>>(x_bf, wqkv_bf, nullptr, qkv_bf,
                                           2048, 6144, 3072, wo, wo_bf);

  // phase 2: RoPE + repack (x4 vectorized), V transpose
  rope_repack<<<5120, 256, 0, stream>>>(qkv_bf, fcos, fsin, q_bf, k_bf);
  vtrans<<<dim3(32, 16), 256, 0, stream>>>(qkv_bf, vt_bf);

  // phase 3/4: attention, output GEMM
  attn_fwd<<<512, 256, 0, stream>>>(q_bf, k_bf, vt_bf, y_bf);
  gemm_bt<0, 0><<<384, 256, 0, stream>>>(y_bf, wo_bf, out, nullptr,
                                         2048, 3072, 4096, nullptr, nullptr);
}

// Round 16
// 311.654 us; speedup vs baseline: 1.0414x; 1.0360x over previous
//
#include <hip/hip_runtime.h>

// ---------- types ----------
typedef __attribute__((ext_vector_type(8))) short bf16x8;
typedef __attribute__((ext_vector_type(4))) float f32x4;

#define T_SEQ   2048
#define DIM     3072
#define NQH     32
#define NKVH    8
#define HD      128
#define QDIM    4096
#define KVDIM   1024
#define QKVDIM  6144

#define AS1 __attribute__((address_space(1)))
#define AS3 __attribute__((address_space(3)))

static __device__ __forceinline__ unsigned short f2bf(float f) {
  unsigned u = __float_as_uint(f);
  u += 0x7FFFu + ((u >> 16) & 1u);          // RNE
  return (unsigned short)(u >> 16);
}
static __device__ __forceinline__ float bf2f(unsigned short h) {
  return __uint_as_float(((unsigned)h) << 16);
}
// packed f32x2 -> bf16x2 (RNE), 1 instruction
static __device__ __forceinline__ unsigned pkbf(float lo, float hi) {
  unsigned r;
  asm("v_cvt_pk_bf16_f32 %0, %1, %2" : "=v"(r) : "v"(lo), "v"(hi));
  return r;
}

// async global->LDS, 16B per lane; LDS dest must be linear in lane order (rule 21)
static __device__ __forceinline__ void gload_lds16(const unsigned short* g, unsigned short* l) {
  __builtin_amdgcn_global_load_lds((AS1 void*)(g), (AS3 void*)(l), 16, 0, 0);
}

// ---------- fused fp32 -> bf16 convert: x, wq, wk, wv, wo in ONE launch ----------
__global__ void cvt_all(const float* __restrict__ x,  const float* __restrict__ wq,
                        const float* __restrict__ wk, const float* __restrict__ wv,
                        const float* __restrict__ wo,
                        unsigned short* __restrict__ xb,
                        unsigned short* __restrict__ wqkvb,
                        unsigned short* __restrict__ wob) {
  const int N0 = 1572864;                    // x:  2048*3072/4
  const int E1 = N0 + 3145728;               // wq: 4096*3072/4
  const int E2 = E1 + 786432;                // wk
  const int E3 = E2 + 786432;                // wv
  const int E4 = E3 + 3145728;               // wo: 3072*4096/4
  const int stride = gridDim.x * blockDim.x;
  for (int i = blockIdx.x * blockDim.x + threadIdx.x; i < E4; i += stride) {
    const float* s; unsigned short* d; int off;
    if (i < N0)      { s = x;  d = xb;               off = i; }
    else if (i < E1) { s = wq; d = wqkvb;            off = i - N0; }
    else if (i < E2) { s = wk; d = wqkvb + 12582912; off = i - E1; }
    else if (i < E3) { s = wv; d = wqkvb + 15728640; off = i - E2; }
    else             { s = wo; d = wob;              off = i - E3; }
    float4 v = reinterpret_cast<const float4*>(s)[off];
    ushort4 o;
    o.x = f2bf(v.x); o.y = f2bf(v.y); o.z = f2bf(v.z); o.w = f2bf(v.w);
    reinterpret_cast<ushort4*>(d + (size_t)off * 4)[0] = o;
  }
}

// ---------- GEMM: C[M,N] = A[M,K] * B[N,K]^T, bf16 in, f32 or bf16 out ----------
// 128x128 tile, 4 waves (2x2 of 64x64), BK=64, m97 structure. COLUMN-panel XCD
// mapping (R13 win): each XCD owns nbx/8 B-columns (L2-resident, fetched once
// per XCD) x all M-panels -> staging loads hit L2 instead of L3/HBM.
template<int OUTBF>
__global__ __launch_bounds__(256) void gemm_bt(
    const unsigned short* __restrict__ A, const unsigned short* __restrict__ B,
    float* __restrict__ Cf, unsigned short* __restrict__ Cb,
    int M, int N, int K) {
  __shared__ unsigned short la[128 * 64];
  __shared__ unsigned short lb[128 * 64];
  const int nbx = N >> 7;
  const int cpx = nbx >> 3;                 // B-column panels per XCD
  const int bid0 = (int)blockIdx.x;
  const int xcd = bid0 & 7;
  const int ii = bid0 >> 3;
  const int bx = cpx * xcd + (ii % cpx);
  const int by = ii / cpx;
  const int tid = threadIdx.x;
  const int ln = tid & 63;
  const int wave = tid >> 6;
  const int lr = ln & 15, lg = ln >> 4;
  const int wr = wave >> 1, wc = wave & 1;
  const int rowA0 = by << 7, rowB0 = bx << 7;

  f32x4 acc[4][4] = {};

  const int ktn = K >> 6;
  for (int kt = 0; kt < ktn; kt++) {
    __syncthreads();                        // prev tile's reads done before overwrite
#pragma unroll
    for (int it = 0; it < 4; it++) {
      int ci = it * 256 + tid;              // linear LDS chunk id (r = ci>>3, pos = ci&7)
      int r = ci >> 3, cpos = ci & 7;
      int c = cpos ^ (r & 7);               // pre-swizzled source chunk
      gload_lds16(A + (size_t)(rowA0 + r) * K + kt * 64 + c * 8, &la[ci * 8]);
      gload_lds16(B + (size_t)(rowB0 + r) * K + kt * 64 + c * 8, &lb[ci * 8]);
    }
    __syncthreads();                        // drains vmcnt -> tiles visible
#pragma unroll
    for (int kk = 0; kk < 2; kk++) {
      bf16x8 af[4], bfr[4];
#pragma unroll
      for (int mi = 0; mi < 4; mi++) {
        int r = wr * 64 + mi * 16 + lr;
        int p = (kk * 4 + lg) ^ (r & 7);
        af[mi] = *reinterpret_cast<const bf16x8*>(&la[r * 64 + p * 8]);
      }
#pragma unroll
      for (int ni = 0; ni < 4; ni++) {
        int r = wc * 64 + ni * 16 + lr;
        int p = (kk * 4 + lg) ^ (r & 7);
        bfr[ni] = *reinterpret_cast<const bf16x8*>(&lb[r * 64 + p * 8]);
      }
#pragma unroll
      for (int mi = 0; mi < 4; mi++)
#pragma unroll
        for (int ni = 0; ni < 4; ni++)
          acc[mi][ni] = __builtin_amdgcn_mfma_f32_16x16x32_bf16(af[mi], bfr[ni], acc[mi][ni], 0, 0, 0);
    }
  }
#pragma unroll
  for (int mi = 0; mi < 4; mi++)
#pragma unroll
    for (int ni = 0; ni < 4; ni++)
#pragma unroll
      for (int j = 0; j < 4; j++) {
        int r = rowA0 + wr * 64 + mi * 16 + lg * 4 + j;   // C/D: row=(l>>4)*4+j, col=l&15
        int cc = rowB0 + wc * 64 + ni * 16 + lr;
        if (OUTBF) Cb[(size_t)r * N + cc] = f2bf(acc[mi][ni][j]);
        else       Cf[(size_t)r * N + cc] = acc[mi][ni][j];
      }
}

// ---------- RoPE + repack (x4 vectorized): qkv [T,6144] -> q [T,4096], k [T,1024] ----------
__global__ void rope_repack(const unsigned short* __restrict__ qkv,
                            const float* __restrict__ fc, const float* __restrict__ fs,
                            unsigned short* __restrict__ qo, unsigned short* __restrict__ ko) {
  int idx = blockIdx.x * blockDim.x + threadIdx.x;   // T * 40 * 16
  int dv = (idx & 15) * 4;                           // d base: 0,4,...,60
  int hh = (idx >> 4) % 40;                          // 0..31 q heads, 32..39 k heads
  int t = idx / 640;
  const unsigned short* src = qkv + (size_t)t * QKVDIM + hh * 128;
  ushort4 xl = *reinterpret_cast<const ushort4*>(src + dv);
  ushort4 xh = *reinterpret_cast<const ushort4*>(src + dv + 64);
  float4 c4 = *reinterpret_cast<const float4*>(&fc[t * 64 + dv]);
  float4 s4 = *reinterpret_cast<const float4*>(&fs[t * 64 + dv]);
  float a0 = bf2f(xl.x), a1 = bf2f(xl.y), a2 = bf2f(xl.z), a3 = bf2f(xl.w);
  float b0 = bf2f(xh.x), b1 = bf2f(xh.y), b2 = bf2f(xh.z), b3 = bf2f(xh.w);
  uint2 lo, hi;
  lo.x = pkbf(a0 * c4.x - b0 * s4.x, a1 * c4.y - b1 * s4.y);
  lo.y = pkbf(a2 * c4.z - b2 * s4.z, a3 * c4.w - b3 * s4.w);
  hi.x = pkbf(b0 * c4.x + a0 * s4.x, b1 * c4.y + a1 * s4.y);
  hi.y = pkbf(b2 * c4.z + a2 * s4.z, b3 * c4.w + a3 * s4.w);
  unsigned short* dst;
  if (hh < 32) { dst = qo + (size_t)t * QDIM + hh * 128; }
  else         { dst = ko + (size_t)t * KVDIM + (hh - 32) * 128; }
  *reinterpret_cast<uint2*>(dst + dv)      = lo;
  *reinterpret_cast<uint2*>(dst + dv + 64) = hi;
}

// ---------- V transpose: qkv[:,5120+c] -> vt[c][t]  (c = kh*128+d) ----------
__global__ void vtrans(const unsigned short* __restrict__ qkv, unsigned short* __restrict__ vt) {
  __shared__ unsigned short tile[64][68];
  int tb = blockIdx.x * 64, cb = blockIdx.y * 64;
  int tid = threadIdx.x;
#pragma unroll
  for (int i = 0; i < 16; i++) {
    int e = i * 256 + tid;
    int tl = e >> 6, cl = e & 63;
    tile[tl][cl] = qkv[(size_t)(tb + tl) * QKVDIM + 5120 + cb + cl];
  }
  __syncthreads();
#pragma unroll
  for (int i = 0; i < 16; i++) {
    int e = i * 256 + tid;
    int cl = e >> 6, tl = e & 63;
    vt[(size_t)(cb + cl) * T_SEQ + tb + tl] = tile[tl][cl];
  }
}

// ---------- causal GQA flash attention (verified R9 version, 512 blocks) ----------
__global__ __launch_bounds__(256) void attn_fwd(
    const unsigned short* __restrict__ q, const unsigned short* __restrict__ k,
    const unsigned short* __restrict__ vt, unsigned short* __restrict__ y) {
  __shared__ unsigned short k_lds[2][32 * 128];
  __shared__ unsigned short v_lds[2][128 * 32];
  __shared__ unsigned short p_lds[4][16 * 40];
  __shared__ float a_lds[4][16];
  const int tid = threadIdx.x;
  const int ln = tid & 63;
  const int wave = tid >> 6;
  const int lr = ln & 15, lg = ln >> 4;

  const int kh = blockIdx.x & 7;
  const int i = blockIdx.x >> 3;
  const int qh = i & 3;
  const int pr = i >> 2;
  const int qta = pr, qtb = 31 - pr;
  const int h = kh * 4 + qh;

  const int qra0 = qta * 64 + wave * 16, qrowa = qra0 + lr;
  const int qrb0 = qtb * 64 + wave * 16, qrowb = qrb0 + lr;
  const float SL2E = 0.08838834764831845f * 1.44269504088896f;
  const float NEGINF = -__builtin_inff();

  bf16x8 qfa[4], qfb[4];
  {
    const unsigned short* qba = q + (size_t)qrowa * QDIM + h * HD + lg * 8;
    const unsigned short* qbb = q + (size_t)qrowb * QDIM + h * HD + lg * 8;
#pragma unroll
    for (int dc = 0; dc < 4; dc++) {
      qfa[dc] = *reinterpret_cast<const bf16x8*>(qba + dc * 32);
      qfb[dc] = *reinterpret_cast<const bf16x8*>(qbb + dc * 32);
    }
  }

  f32x4 acca[8] = {}, accb[8] = {};
  float ma = NEGINF, la = 0.f, mb = NEGINF, lb = 0.f;

  const int krow0 = tid >> 4,  kcol0 = tid & 15;
  const int krow1 = 16 + krow0;
  const int vrow0 = tid >> 2,  vcol0 = tid & 3;
  const int vrow1 = 64 + vrow0;

  auto tile_compute = [&](int sb, int cur, const bf16x8 (&qf)[4], f32x4 (&acc)[8],
                          float& m, float& lsum, int qr0, int qrow) {
    f32x4 s0t = {0.f, 0.f, 0.f, 0.f}, s1t = {0.f, 0.f, 0.f, 0.f};
    __builtin_amdgcn_s_setprio(1);
#pragma unroll
    for (int dc = 0; dc < 4; dc++) {
      int c = lg + dc * 4;
      int p = c ^ (lr & 7);
      bf16x8 a0 = *reinterpret_cast<const bf16x8*>(&k_lds[cur][lr * 128 + p * 8]);
      bf16x8 a1 = *reinterpret_cast<const bf16x8*>(&k_lds[cur][(lr + 16) * 128 + p * 8]);
      s0t = __builtin_amdgcn_mfma_f32_16x16x32_bf16(a0, qf[dc], s0t, 0, 0, 0);
      s1t = __builtin_amdgcn_mfma_f32_16x16x32_bf16(a1, qf[dc], s1t, 0, 0, 0);
    }
    __builtin_amdgcn_s_setprio(0);

    float vv[8];
    if (sb + 31 <= qr0) {
#pragma unroll
      for (int jj = 0; jj < 4; jj++) { vv[jj] = s0t[jj]; vv[jj + 4] = s1t[jj]; }
    } else {
      const int base0 = sb + lg * 4;
#pragma unroll
      for (int jj = 0; jj < 4; jj++) {
        vv[jj]     = (base0 + jj      <= qrow) ? s0t[jj] : NEGINF;
        vv[jj + 4] = (base0 + jj + 16 <= qrow) ? s1t[jj] : NEGINF;
      }
    }

    float mx = fmaxf(fmaxf(fmaxf(vv[0], vv[1]), fmaxf(vv[2], vv[3])),
                     fmaxf(fmaxf(vv[4], vv[5]), fmaxf(vv[6], vv[7])));
    mx = fmaxf(mx, __shfl_xor(mx, 16));
    mx = fmaxf(mx, __shfl_xor(mx, 32));

    const bool doresc = __any(mx > m + 60.0f);
    const float mn = doresc ? fmaxf(m, mx) : m;

    float p[8], ps = 0.f;
#pragma unroll
    for (int ii = 0; ii < 8; ii++) { p[ii] = exp2f((vv[ii] - mn) * SL2E); ps += p[ii]; }
    ps += __shfl_xor(ps, 16);
    ps += __shfl_xor(ps, 32);

    uint2 w0, w1;
    w0.x = pkbf(p[0], p[1]); w0.y = pkbf(p[2], p[3]);
    w1.x = pkbf(p[4], p[5]); w1.y = pkbf(p[6], p[7]);
    *reinterpret_cast<uint2*>(&p_lds[wave][lr * 40 + lg * 4])      = w0;
    *reinterpret_cast<uint2*>(&p_lds[wave][lr * 40 + 16 + lg * 4]) = w1;

    if (doresc) {
      const float alpha = exp2f((m - mn) * SL2E);
      lsum = lsum * alpha + ps;
      m = mn;
      a_lds[wave][lr] = alpha;
      asm volatile("s_waitcnt lgkmcnt(0)" ::: "memory");
      float4 a4 = *reinterpret_cast<const float4*>(&a_lds[wave][lg * 4]);
#pragma unroll
      for (int dc2 = 0; dc2 < 8; dc2++) {
        acc[dc2][0] *= a4.x; acc[dc2][1] *= a4.y;
        acc[dc2][2] *= a4.z; acc[dc2][3] *= a4.w;
      }
    } else {
      lsum += ps;
      asm volatile("s_waitcnt lgkmcnt(0)" ::: "memory");
    }

    bf16x8 pa = *reinterpret_cast<const bf16x8*>(&p_lds[wave][lr * 40 + lg * 8]);
    __builtin_amdgcn_s_setprio(1);
#pragma unroll
    for (int dc2 = 0; dc2 < 8; dc2++) {
      int d = dc2 * 16 + lr;
      int p2 = lg ^ ((d >> 1) & 3);
      bf16x8 bv = *reinterpret_cast<const bf16x8*>(&v_lds[cur][d * 32 + p2 * 8]);
      acc[dc2] = __builtin_amdgcn_mfma_f32_16x16x32_bf16(pa, bv, acc[dc2], 0, 0, 0);
    }
    __builtin_amdgcn_s_setprio(0);
  };

  const int ntiles = (qtb * 64 + 95) >> 5;

  {
    bf16x8 kr0 = *reinterpret_cast<const bf16x8*>(k + (size_t)krow0 * KVDIM + kh * HD + kcol0 * 8);
    bf16x8 kr1 = *reinterpret_cast<const bf16x8*>(k + (size_t)krow1 * KVDIM + kh * HD + kcol0 * 8);
    bf16x8 vr0 = *reinterpret_cast<const bf16x8*>(vt + (size_t)(kh * HD + vrow0) * T_SEQ + vcol0 * 8);
    bf16x8 vr1 = *reinterpret_cast<const bf16x8*>(vt + (size_t)(kh * HD + vrow1) * T_SEQ + vcol0 * 8);
    *reinterpret_cast<bf16x8*>(&k_lds[0][krow0 * 128 + (kcol0 ^ (krow0 & 7)) * 8]) = kr0;
    *reinterpret_cast<bf16x8*>(&k_lds[0][krow1 * 128 + (kcol0 ^ (krow1 & 7)) * 8]) = kr1;
    *reinterpret_cast<bf16x8*>(&v_lds[0][vrow0 * 32 + (vcol0 ^ ((vrow0 >> 1) & 3)) * 8]) = vr0;
    *reinterpret_cast<bf16x8*>(&v_lds[0][vrow1 * 32 + (vcol0 ^ ((vrow1 >> 1) & 3)) * 8]) = vr1;
  }
  __syncthreads();

  for (int st = 0; st < ntiles; st++) {
    const int sb = st * 32;
    const int cur = st & 1;
    const bool more = (st + 1 < ntiles);

    bf16x8 kr0, kr1, vr0, vr1;
    if (more) {
      const int sb1 = sb + 32;
      kr0 = *reinterpret_cast<const bf16x8*>(k + (size_t)(sb1 + krow0) * KVDIM + kh * HD + kcol0 * 8);
      kr1 = *reinterpret_cast<const bf16x8*>(k + (size_t)(sb1 + krow1) * KVDIM + kh * HD + kcol0 * 8);
      vr0 = *reinterpret_cast<const bf16x8*>(vt + (size_t)(kh * HD + vrow0) * T_SEQ + sb1 + vcol0 * 8);
      vr1 = *reinterpret_cast<const bf16x8*>(vt + (size_t)(kh * HD + vrow1) * T_SEQ + sb1 + vcol0 * 8);
    }

    if (sb <= qrb0 + 15) tile_compute(sb, cur, qfb, accb, mb, lb, qrb0, qrowb);
    if (sb <= qra0 + 15) tile_compute(sb, cur, qfa, acca, ma, la, qra0, qrowa);

    if (more) {
      const int nxt = cur ^ 1;
      *reinterpret_cast<bf16x8*>(&k_lds[nxt][krow0 * 128 + (kcol0 ^ (krow0 & 7)) * 8]) = kr0;
      *reinterpret_cast<bf16x8*>(&k_lds[nxt][krow1 * 128 + (kcol0 ^ (krow1 & 7)) * 8]) = kr1;
      *reinterpret_cast<bf16x8*>(&v_lds[nxt][vrow0 * 32 + (vcol0 ^ ((vrow0 >> 1) & 3)) * 8]) = vr0;
      *reinterpret_cast<bf16x8*>(&v_lds[nxt][vrow1 * 32 + (vcol0 ^ ((vrow1 >> 1) & 3)) * 8]) = vr1;
      __syncthreads();
    }
  }

  a_lds[wave][lr] = 1.0f / lb;
  asm volatile("s_waitcnt lgkmcnt(0)" ::: "memory");
  float4 l4 = *reinterpret_cast<const float4*>(&a_lds[wave][lg * 4]);
  {
    float li[4] = {l4.x, l4.y, l4.z, l4.w};
#pragma unroll
    for (int jj = 0; jj < 4; jj++) {
      int r = qrb0 + lg * 4 + jj;
#pragma unroll
      for (int dc2 = 0; dc2 < 8; dc2++)
        y[(size_t)r * QDIM + h * HD + dc2 * 16 + lr] = f2bf(accb[dc2][jj] * li[jj]);
    }
  }
  a_lds[wave][lr] = 1.0f / la;
  asm volatile("s_waitcnt lgkmcnt(0)" ::: "memory");
  l4 = *reinterpret_cast<const float4*>(&a_lds[wave][lg * 4]);
  {
    float li[4] = {l4.x, l4.y, l4.z, l4.w};
#pragma unroll
    for (int jj = 0; jj < 4; jj++) {
      int r = qra0 + lg * 4 + jj;
#pragma unroll
      for (int dc2 = 0; dc2 < 8; dc2++)
        y[(size_t)r * QDIM + h * HD + dc2 * 16 + lr] = f2bf(acca[dc2][jj] * li[jj]);
    }
  }
}

// ---------- launch ----------
extern "C" void kernel_launch(void* const* d_in, const int* in_sizes, int n_in,
                              void* d_out, int out_size, void* d_ws, size_t ws_size,
                              hipStream_t stream) {
  (void)in_sizes; (void)n_in; (void)out_size; (void)ws_size;
  const float* x    = (const float*)d_in[0];
  const float* fcos = (const float*)d_in[1];
  const float* fsin = (const float*)d_in[2];
  const float* wq   = (const float*)d_in[4];
  const float* wk   = (const float*)d_in[5];
  const float* wv   = (const float*)d_in[6];
  const float* wo   = (const float*)d_in[7];
  float* out = (float*)d_out;
  char* ws = (char*)d_ws;

  // workspace layout (peak 100.7 MB)
  unsigned short* x_bf    = (unsigned short*)(ws);                    // 12.6 MB [phase 1]
  unsigned short* wqkv_bf = (unsigned short*)(ws + 12582912);         // 37.7 MB [phase 1]
  unsigned short* qkv_bf  = (unsigned short*)(ws + 50331648);         // 25.2 MB [phase 1-2]
  unsigned short* q_bf    = (unsigned short*)(ws);                    // 16.8 MB [phase 2+]
  unsigned short* k_bf    = (unsigned short*)(ws + 16777216);         //  4.2 MB
  unsigned short* vt_bf   = (unsigned short*)(ws + 20971520);         //  4.2 MB
  unsigned short* y_bf    = (unsigned short*)(ws + 25165824);         // 16.8 MB
  unsigned short* wo_bf   = (unsigned short*)(ws + 75497472);         // 25.2 MB (own region)

  // phase 1: fused converts (one launch), QKV GEMM
  cvt_all<<<4096, 256, 0, stream>>>(x, wq, wk, wv, wo, x_bf, wqkv_bf, wo_bf);
  gemm_bt<1><<<768, 256, 0, stream>>>(x_bf, wqkv_bf, nullptr, qkv_bf, 2048, 6144, 3072);

  // phase 2: RoPE + repack (x4 vectorized), V transpose
  rope_repack<<<5120, 256, 0, stream>>>(qkv_bf, fcos, fsin, q_bf, k_bf);
  vtrans<<<dim3(32, 16), 256, 0, stream>>>(qkv_bf, vt_bf);

  // phase 3/4: attention, output GEMM
  attn_fwd<<<512, 256, 0, stream>>>(q_bf, k_bf, vt_bf, y_bf);
  gemm_bt<0><<<384, 256, 0, stream>>>(y_bf, wo_bf, out, nullptr, 2048, 3072, 4096);
}

// Round 17
// 305.241 us; speedup vs baseline: 1.0633x; 1.0210x over previous
//
#include <hip/hip_runtime.h>

// ---------- types ----------
typedef __attribute__((ext_vector_type(8))) short bf16x8;
typedef __attribute__((ext_vector_type(4))) float f32x4;

#define T_SEQ   2048
#define DIM     3072
#define NQH     32
#define NKVH    8
#define HD      128
#define QDIM    4096
#define KVDIM   1024
#define QKVDIM  6144

#define AS1 __attribute__((address_space(1)))
#define AS3 __attribute__((address_space(3)))

static __device__ __forceinline__ unsigned short f2bf(float f) {
  unsigned u = __float_as_uint(f);
  u += 0x7FFFu + ((u >> 16) & 1u);          // RNE
  return (unsigned short)(u >> 16);
}
static __device__ __forceinline__ float bf2f(unsigned short h) {
  return __uint_as_float(((unsigned)h) << 16);
}
// packed f32x2 -> bf16x2 (RNE), 1 instruction
static __device__ __forceinline__ unsigned pkbf(float lo, float hi) {
  unsigned r;
  asm("v_cvt_pk_bf16_f32 %0, %1, %2" : "=v"(r) : "v"(lo), "v"(hi));
  return r;
}

// async global->LDS, 16B per lane; LDS dest must be linear in lane order (rule 21)
static __device__ __forceinline__ void gload_lds16(const unsigned short* g, unsigned short* l) {
  __builtin_amdgcn_global_load_lds((AS1 void*)(g), (AS3 void*)(l), 16, 0, 0);
}

// ---------- fused fp32 -> bf16 convert: x, wq, wk, wv, wo in ONE launch ----------
__global__ void cvt_all(const float* __restrict__ x,  const float* __restrict__ wq,
                        const float* __restrict__ wk, const float* __restrict__ wv,
                        const float* __restrict__ wo,
                        unsigned short* __restrict__ xb,
                        unsigned short* __restrict__ wqkvb,
                        unsigned short* __restrict__ wob) {
  const int N0 = 1572864;                    // x:  2048*3072/4
  const int E1 = N0 + 3145728;               // wq: 4096*3072/4
  const int E2 = E1 + 786432;                // wk
  const int E3 = E2 + 786432;                // wv
  const int E4 = E3 + 3145728;               // wo: 3072*4096/4
  const int stride = gridDim.x * blockDim.x;
  for (int i = blockIdx.x * blockDim.x + threadIdx.x; i < E4; i += stride) {
    const float* s; unsigned short* d; int off;
    if (i < N0)      { s = x;  d = xb;               off = i; }
    else if (i < E1) { s = wq; d = wqkvb;            off = i - N0; }
    else if (i < E2) { s = wk; d = wqkvb + 12582912; off = i - E1; }
    else if (i < E3) { s = wv; d = wqkvb + 15728640; off = i - E2; }
    else             { s = wo; d = wob;              off = i - E3; }
    float4 v = reinterpret_cast<const float4*>(s)[off];
    ushort4 o;
    o.x = f2bf(v.x); o.y = f2bf(v.y); o.z = f2bf(v.z); o.w = f2bf(v.w);
    reinterpret_cast<ushort4*>(d + (size_t)off * 4)[0] = o;
  }
}

// ---------- GEMM: C[M,N] = A[M,K] * B[N,K]^T, bf16 in, f32 or bf16 out ----------
// 128x128 tile, 4 waves (2x2 of 64x64), BK=64, m97 structure. COLUMN-panel XCD
// mapping (R13 win): each XCD owns nbx/8 B-columns (L2-resident, fetched once
// per XCD) x all M-panels -> staging loads hit L2 instead of L3/HBM.
template<int OUTBF>
__global__ __launch_bounds__(256) void gemm_bt(
    const unsigned short* __restrict__ A, const unsigned short* __restrict__ B,
    float* __restrict__ Cf, unsigned short* __restrict__ Cb,
    int M, int N, int K) {
  __shared__ unsigned short la[128 * 64];
  __shared__ unsigned short lb[128 * 64];
  const int nbx = N >> 7;
  const int cpx = nbx >> 3;                 // B-column panels per XCD
  const int bid0 = (int)blockIdx.x;
  const int xcd = bid0 & 7;
  const int ii = bid0 >> 3;
  const int bx = cpx * xcd + (ii % cpx);
  const int by = ii / cpx;
  const int tid = threadIdx.x;
  const int ln = tid & 63;
  const int wave = tid >> 6;
  const int lr = ln & 15, lg = ln >> 4;
  const int wr = wave >> 1, wc = wave & 1;
  const int rowA0 = by << 7, rowB0 = bx << 7;

  f32x4 acc[4][4] = {};

  const int ktn = K >> 6;
  for (int kt = 0; kt < ktn; kt++) {
    __syncthreads();                        // prev tile's reads done before overwrite
#pragma unroll
    for (int it = 0; it < 4; it++) {
      int ci = it * 256 + tid;              // linear LDS chunk id (r = ci>>3, pos = ci&7)
      int r = ci >> 3, cpos = ci & 7;
      int c = cpos ^ (r & 7);               // pre-swizzled source chunk
      gload_lds16(A + (size_t)(rowA0 + r) * K + kt * 64 + c * 8, &la[ci * 8]);
      gload_lds16(B + (size_t)(rowB0 + r) * K + kt * 64 + c * 8, &lb[ci * 8]);
    }
    __syncthreads();                        // drains vmcnt -> tiles visible
#pragma unroll
    for (int kk = 0; kk < 2; kk++) {
      bf16x8 af[4], bfr[4];
#pragma unroll
      for (int mi = 0; mi < 4; mi++) {
        int r = wr * 64 + mi * 16 + lr;
        int p = (kk * 4 + lg) ^ (r & 7);
        af[mi] = *reinterpret_cast<const bf16x8*>(&la[r * 64 + p * 8]);
      }
#pragma unroll
      for (int ni = 0; ni < 4; ni++) {
        int r = wc * 64 + ni * 16 + lr;
        int p = (kk * 4 + lg) ^ (r & 7);
        bfr[ni] = *reinterpret_cast<const bf16x8*>(&lb[r * 64 + p * 8]);
      }
#pragma unroll
      for (int mi = 0; mi < 4; mi++)
#pragma unroll
        for (int ni = 0; ni < 4; ni++)
          acc[mi][ni] = __builtin_amdgcn_mfma_f32_16x16x32_bf16(af[mi], bfr[ni], acc[mi][ni], 0, 0, 0);
    }
  }
#pragma unroll
  for (int mi = 0; mi < 4; mi++)
#pragma unroll
    for (int ni = 0; ni < 4; ni++)
#pragma unroll
      for (int j = 0; j < 4; j++) {
        int r = rowA0 + wr * 64 + mi * 16 + lg * 4 + j;   // C/D: row=(l>>4)*4+j, col=l&15
        int cc = rowB0 + wc * 64 + ni * 16 + lr;
        if (OUTBF) Cb[(size_t)r * N + cc] = f2bf(acc[mi][ni][j]);
        else       Cf[(size_t)r * N + cc] = acc[mi][ni][j];
      }
}

// ---------- RoPE repack (x4 vectorized) + V transpose, ONE launch ----------
// Blocks 0..5119: rope (q/k). Blocks 5120..5631: vtrans (512 blocks of 64x64).
__global__ void rope_vt(const unsigned short* __restrict__ qkv,
                        const float* __restrict__ fc, const float* __restrict__ fs,
                        unsigned short* __restrict__ qo, unsigned short* __restrict__ ko,
                        unsigned short* __restrict__ vt) {
  const int tid = threadIdx.x;
  if ((int)blockIdx.x >= 5120) {
    __shared__ unsigned short tile[64][68];
    int b = (int)blockIdx.x - 5120;         // 0..511 = (tb 0..31) x (cb 0..15)
    int tb = (b & 31) * 64, cb = (b >> 5) * 64;
#pragma unroll
    for (int i = 0; i < 16; i++) {
      int e = i * 256 + tid;
      int tl = e >> 6, cl = e & 63;
      tile[tl][cl] = qkv[(size_t)(tb + tl) * QKVDIM + 5120 + cb + cl];
    }
    __syncthreads();
#pragma unroll
    for (int i = 0; i < 16; i++) {
      int e = i * 256 + tid;
      int cl = e >> 6, tl = e & 63;
      vt[(size_t)(cb + cl) * T_SEQ + tb + tl] = tile[tl][cl];
    }
    return;
  }
  int idx = blockIdx.x * 256 + tid;         // T * 40 * 16
  int dv = (idx & 15) * 4;                  // d base: 0,4,...,60
  int hh = (idx >> 4) % 40;                 // 0..31 q heads, 32..39 k heads
  int t = idx / 640;
  const unsigned short* src = qkv + (size_t)t * QKVDIM + hh * 128;
  ushort4 xl = *reinterpret_cast<const ushort4*>(src + dv);
  ushort4 xh = *reinterpret_cast<const ushort4*>(src + dv + 64);
  float4 c4 = *reinterpret_cast<const float4*>(&fc[t * 64 + dv]);
  float4 s4 = *reinterpret_cast<const float4*>(&fs[t * 64 + dv]);
  float a0 = bf2f(xl.x), a1 = bf2f(xl.y), a2 = bf2f(xl.z), a3 = bf2f(xl.w);
  float b0 = bf2f(xh.x), b1 = bf2f(xh.y), b2 = bf2f(xh.z), b3 = bf2f(xh.w);
  uint2 lo, hi;
  lo.x = pkbf(a0 * c4.x - b0 * s4.x, a1 * c4.y - b1 * s4.y);
  lo.y = pkbf(a2 * c4.z - b2 * s4.z, a3 * c4.w - b3 * s4.w);
  hi.x = pkbf(b0 * c4.x + a0 * s4.x, b1 * c4.y + a1 * s4.y);
  hi.y = pkbf(b2 * c4.z + a2 * s4.z, b3 * c4.w + a3 * s4.w);
  unsigned short* dst;
  if (hh < 32) { dst = qo + (size_t)t * QDIM + hh * 128; }
  else         { dst = ko + (size_t)t * KVDIM + (hh - 32) * 128; }
  *reinterpret_cast<uint2*>(dst + dv)      = lo;
  *reinterpret_cast<uint2*>(dst + dv + 64) = hi;
}

// ---------- causal GQA flash attention (verified R9 structure, 512 blocks) ----------
// Micro-opts this round: fma-folded exp2 args (2 ops/score vs 3), max3-friendly
// reduction nesting (v_max3_f32).
__global__ __launch_bounds__(256) void attn_fwd(
    const unsigned short* __restrict__ q, const unsigned short* __restrict__ k,
    const unsigned short* __restrict__ vt, unsigned short* __restrict__ y) {
  __shared__ unsigned short k_lds[2][32 * 128];
  __shared__ unsigned short v_lds[2][128 * 32];
  __shared__ unsigned short p_lds[4][16 * 40];
  __shared__ float a_lds[4][16];
  const int tid = threadIdx.x;
  const int ln = tid & 63;
  const int wave = tid >> 6;
  const int lr = ln & 15, lg = ln >> 4;

  const int kh = blockIdx.x & 7;
  const int i = blockIdx.x >> 3;
  const int qh = i & 3;
  const int pr = i >> 2;
  const int qta = pr, qtb = 31 - pr;
  const int h = kh * 4 + qh;

  const int qra0 = qta * 64 + wave * 16, qrowa = qra0 + lr;
  const int qrb0 = qtb * 64 + wave * 16, qrowb = qrb0 + lr;
  const float SL2E = 0.08838834764831845f * 1.44269504088896f;  // scale * log2(e)
  const float NEGINF = -__builtin_inff();

  bf16x8 qfa[4], qfb[4];
  {
    const unsigned short* qba = q + (size_t)qrowa * QDIM + h * HD + lg * 8;
    const unsigned short* qbb = q + (size_t)qrowb * QDIM + h * HD + lg * 8;
#pragma unroll
    for (int dc = 0; dc < 4; dc++) {
      qfa[dc] = *reinterpret_cast<const bf16x8*>(qba + dc * 32);
      qfb[dc] = *reinterpret_cast<const bf16x8*>(qbb + dc * 32);
    }
  }

  f32x4 acca[8] = {}, accb[8] = {};
  float ma = NEGINF, la = 0.f, mb = NEGINF, lb = 0.f;

  const int krow0 = tid >> 4,  kcol0 = tid & 15;
  const int krow1 = 16 + krow0;
  const int vrow0 = tid >> 2,  vcol0 = tid & 3;
  const int vrow1 = 64 + vrow0;

  auto tile_compute = [&](int sb, int cur, const bf16x8 (&qf)[4], f32x4 (&acc)[8],
                          float& m, float& lsum, int qr0, int qrow) {
    f32x4 s0t = {0.f, 0.f, 0.f, 0.f}, s1t = {0.f, 0.f, 0.f, 0.f};
    __builtin_amdgcn_s_setprio(1);
#pragma unroll
    for (int dc = 0; dc < 4; dc++) {
      int c = lg + dc * 4;
      int p = c ^ (lr & 7);
      bf16x8 a0 = *reinterpret_cast<const bf16x8*>(&k_lds[cur][lr * 128 + p * 8]);
      bf16x8 a1 = *reinterpret_cast<const bf16x8*>(&k_lds[cur][(lr + 16) * 128 + p * 8]);
      s0t = __builtin_amdgcn_mfma_f32_16x16x32_bf16(a0, qf[dc], s0t, 0, 0, 0);
      s1t = __builtin_amdgcn_mfma_f32_16x16x32_bf16(a1, qf[dc], s1t, 0, 0, 0);
    }
    __builtin_amdgcn_s_setprio(0);

    float vv[8];
    if (sb + 31 <= qr0) {
#pragma unroll
      for (int jj = 0; jj < 4; jj++) { vv[jj] = s0t[jj]; vv[jj + 4] = s1t[jj]; }
    } else {
      const int base0 = sb + lg * 4;
#pragma unroll
      for (int jj = 0; jj < 4; jj++) {
        vv[jj]     = (base0 + jj      <= qrow) ? s0t[jj] : NEGINF;
        vv[jj + 4] = (base0 + jj + 16 <= qrow) ? s1t[jj] : NEGINF;
      }
    }

    // row max: max3-friendly nesting (v_max3_f32) + 2 cross-lane
    float mx = fmaxf(fmaxf(fmaxf(fmaxf(vv[0], vv[1]), vv[2]),
                           fmaxf(fmaxf(vv[3], vv[4]), vv[5])),
                     fmaxf(vv[6], vv[7]));
    mx = fmaxf(mx, __shfl_xor(mx, 16));
    mx = fmaxf(mx, __shfl_xor(mx, 32));

    const bool doresc = __any(mx > m + 60.0f);
    const float mn = doresc ? fmaxf(m, mx) : m;
    const float mns = mn * SL2E;             // fold: exp2(vv*SL2E - mns) = fma+exp

    float p[8], ps = 0.f;
#pragma unroll
    for (int ii = 0; ii < 8; ii++) {
      p[ii] = exp2f(__builtin_fmaf(vv[ii], SL2E, -mns));
      ps += p[ii];
    }
    ps += __shfl_xor(ps, 16);
    ps += __shfl_xor(ps, 32);

    uint2 w0, w1;
    w0.x = pkbf(p[0], p[1]); w0.y = pkbf(p[2], p[3]);
    w1.x = pkbf(p[4], p[5]); w1.y = pkbf(p[6], p[7]);
    *reinterpret_cast<uint2*>(&p_lds[wave][lr * 40 + lg * 4])      = w0;
    *reinterpret_cast<uint2*>(&p_lds[wave][lr * 40 + 16 + lg * 4]) = w1;

    if (doresc) {
      const float alpha = exp2f((m - mn) * SL2E);
      lsum = lsum * alpha + ps;
      m = mn;
      a_lds[wave][lr] = alpha;
      asm volatile("s_waitcnt lgkmcnt(0)" ::: "memory");
      float4 a4 = *reinterpret_cast<const float4*>(&a_lds[wave][lg * 4]);
#pragma unroll
      for (int dc2 = 0; dc2 < 8; dc2++) {
        acc[dc2][0] *= a4.x; acc[dc2][1] *= a4.y;
        acc[dc2][2] *= a4.z; acc[dc2][3] *= a4.w;
      }
    } else {
      lsum += ps;
      asm volatile("s_waitcnt lgkmcnt(0)" ::: "memory");
    }

    bf16x8 pa = *reinterpret_cast<const bf16x8*>(&p_lds[wave][lr * 40 + lg * 8]);
    __builtin_amdgcn_s_setprio(1);
#pragma unroll
    for (int dc2 = 0; dc2 < 8; dc2++) {
      int d = dc2 * 16 + lr;
      int p2 = lg ^ ((d >> 1) & 3);
      bf16x8 bv = *reinterpret_cast<const bf16x8*>(&v_lds[cur][d * 32 + p2 * 8]);
      acc[dc2] = __builtin_amdgcn_mfma_f32_16x16x32_bf16(pa, bv, acc[dc2], 0, 0, 0);
    }
    __builtin_amdgcn_s_setprio(0);
  };

  const int ntiles = (qtb * 64 + 95) >> 5;

  {
    bf16x8 kr0 = *reinterpret_cast<const bf16x8*>(k + (size_t)krow0 * KVDIM + kh * HD + kcol0 * 8);
    bf16x8 kr1 = *reinterpret_cast<const bf16x8*>(k + (size_t)krow1 * KVDIM + kh * HD + kcol0 * 8);
    bf16x8 vr0 = *reinterpret_cast<const bf16x8*>(vt + (size_t)(kh * HD + vrow0) * T_SEQ + vcol0 * 8);
    bf16x8 vr1 = *reinterpret_cast<const bf16x8*>(vt + (size_t)(kh * HD + vrow1) * T_SEQ + vcol0 * 8);
    *reinterpret_cast<bf16x8*>(&k_lds[0][krow0 * 128 + (kcol0 ^ (krow0 & 7)) * 8]) = kr0;
    *reinterpret_cast<bf16x8*>(&k_lds[0][krow1 * 128 + (kcol0 ^ (krow1 & 7)) * 8]) = kr1;
    *reinterpret_cast<bf16x8*>(&v_lds[0][vrow0 * 32 + (vcol0 ^ ((vrow0 >> 1) & 3)) * 8]) = vr0;
    *reinterpret_cast<bf16x8*>(&v_lds[0][vrow1 * 32 + (vcol0 ^ ((vrow1 >> 1) & 3)) * 8]) = vr1;
  }
  __syncthreads();

  for (int st = 0; st < ntiles; st++) {
    const int sb = st * 32;
    const int cur = st & 1;
    const bool more = (st + 1 < ntiles);

    bf16x8 kr0, kr1, vr0, vr1;
    if (more) {
      const int sb1 = sb + 32;
      kr0 = *reinterpret_cast<const bf16x8*>(k + (size_t)(sb1 + krow0) * KVDIM + kh * HD + kcol0 * 8);
      kr1 = *reinterpret_cast<const bf16x8*>(k + (size_t)(sb1 + krow1) * KVDIM + kh * HD + kcol0 * 8);
      vr0 = *reinterpret_cast<const bf16x8*>(vt + (size_t)(kh * HD + vrow0) * T_SEQ + sb1 + vcol0 * 8);
      vr1 = *reinterpret_cast<const bf16x8*>(vt + (size_t)(kh * HD + vrow1) * T_SEQ + sb1 + vcol0 * 8);
    }

    if (sb <= qrb0 + 15) tile_compute(sb, cur, qfb, accb, mb, lb, qrb0, qrowb);
    if (sb <= qra0 + 15) tile_compute(sb, cur, qfa, acca, ma, la, qra0, qrowa);

    if (more) {
      const int nxt = cur ^ 1;
      *reinterpret_cast<bf16x8*>(&k_lds[nxt][krow0 * 128 + (kcol0 ^ (krow0 & 7)) * 8]) = kr0;
      *reinterpret_cast<bf16x8*>(&k_lds[nxt][krow1 * 128 + (kcol0 ^ (krow1 & 7)) * 8]) = kr1;
      *reinterpret_cast<bf16x8*>(&v_lds[nxt][vrow0 * 32 + (vcol0 ^ ((vrow0 >> 1) & 3)) * 8]) = vr0;
      *reinterpret_cast<bf16x8*>(&v_lds[nxt][vrow1 * 32 + (vcol0 ^ ((vrow1 >> 1) & 3)) * 8]) = vr1;
      __syncthreads();
    }
  }

  a_lds[wave][lr] = 1.0f / lb;
  asm volatile("s_waitcnt lgkmcnt(0)" ::: "memory");
  float4 l4 = *reinterpret_cast<const float4*>(&a_lds[wave][lg * 4]);
  {
    float li[4] = {l4.x, l4.y, l4.z, l4.w};
#pragma unroll
    for (int jj = 0; jj < 4; jj++) {
      int r = qrb0 + lg * 4 + jj;
#pragma unroll
      for (int dc2 = 0; dc2 < 8; dc2++)
        y[(size_t)r * QDIM + h * HD + dc2 * 16 + lr] = f2bf(accb[dc2][jj] * li[jj]);
    }
  }
  a_lds[wave][lr] = 1.0f / la;
  asm volatile("s_waitcnt lgkmcnt(0)" ::: "memory");
  l4 = *reinterpret_cast<const float4*>(&a_lds[wave][lg * 4]);
  {
    float li[4] = {l4.x, l4.y, l4.z, l4.w};
#pragma unroll
    for (int jj = 0; jj < 4; jj++) {
      int r = qra0 + lg * 4 + jj;
#pragma unroll
      for (int dc2 = 0; dc2 < 8; dc2++)
        y[(size_t)r * QDIM + h * HD + dc2 * 16 + lr] = f2bf(acca[dc2][jj] * li[jj]);
    }
  }
}

// ---------- launch ----------
extern "C" void kernel_launch(void* const* d_in, const int* in_sizes, int n_in,
                              void* d_out, int out_size, void* d_ws, size_t ws_size,
                              hipStream_t stream) {
  (void)in_sizes; (void)n_in; (void)out_size; (void)ws_size;
  const float* x    = (const float*)d_in[0];
  const float* fcos = (const float*)d_in[1];
  const float* fsin = (const float*)d_in[2];
  const float* wq   = (const float*)d_in[4];
  const float* wk   = (const float*)d_in[5];
  const float* wv   = (const float*)d_in[6];
  const float* wo   = (const float*)d_in[7];
  float* out = (float*)d_out;
  char* ws = (char*)d_ws;

  // workspace layout (peak 100.7 MB)
  unsigned short* x_bf    = (unsigned short*)(ws);                    // 12.6 MB [phase 1]
  unsigned short* wqkv_bf = (unsigned short*)(ws + 12582912);         // 37.7 MB [phase 1]
  unsigned short* qkv_bf  = (unsigned short*)(ws + 50331648);         // 25.2 MB [phase 1-2]
  unsigned short* q_bf    = (unsigned short*)(ws);                    // 16.8 MB [phase 2+]
  unsigned short* k_bf    = (unsigned short*)(ws + 16777216);         //  4.2 MB
  unsigned short* vt_bf   = (unsigned short*)(ws + 20971520);         //  4.2 MB
  unsigned short* y_bf    = (unsigned short*)(ws + 25165824);         // 16.8 MB
  unsigned short* wo_bf   = (unsigned short*)(ws + 75497472);         // 25.2 MB (own region)

  // phase 1: fused converts (one launch), QKV GEMM
  cvt_all<<<4096, 256, 0, stream>>>(x, wq, wk, wv, wo, x_bf, wqkv_bf, wo_bf);
  gemm_bt<1><<<768, 256, 0, stream>>>(x_bf, wqkv_bf, nullptr, qkv_bf, 2048, 6144, 3072);

  // phase 2: RoPE repack + V transpose (one launch)
  rope_vt<<<5632, 256, 0, stream>>>(qkv_bf, fcos, fsin, q_bf, k_bf, vt_bf);

  // phase 3/4: attention, output GEMM
  attn_fwd<<<512, 256, 0, stream>>>(q_bf, k_bf, vt_bf, y_bf);
  gemm_bt<0><<<384, 256, 0, stream>>>(y_bf, wo_bf, out, nullptr, 2048, 3072, 4096);
}